// Round 3
// baseline (307.290 us; speedup 1.0000x reference)
//
#include <hip/hip_runtime.h>
#include <math.h>

#define L 4096
#define B 8
#define D 1024
#define NH 16
#define COUT 128              // output chunk per block
#define WB 128                // windback length (q^128 <= 2.4e-6 worst-case here)
#define NCHUNK (L / COUT)     // 32
#define BD 8192               // B*D floats between consecutive l
#define DBLK 128              // d-values per block
#define TL 8                  // l-rows per tile (1KB per wave-tile)
#define NBUF 4                // quad-buffered per-wave LDS

#define REP8(F)  F(0) F(1) F(2) F(3) F(4) F(5) F(6) F(7)

__device__ __forceinline__ float sigmoidf(float v) {
    return 1.0f / (1.0f + __expf(-v));
}

// Per-head update/accumulate (8 heads per thread; lane pairs split 16 heads).
#define UPD(i) s##i = fmaf(q##i, s##i, xv);
#define UPDALL UPD(0) UPD(1) UPD(2) UPD(3) UPD(4) UPD(5) UPD(6) UPD(7)
#define ACC(i) s##i = fmaf(q##i, s##i, xv); y = fmaf(P##i, s##i, y);
#define ACCALL ACC(0) ACC(1) ACC(2) ACC(3) ACC(4) ACC(5) ACC(6) ACC(7)

// async global->LDS, 16B/lane. LDS dest = wave-uniform base + lane*16.
// One instr stages 8 rows x 32 cols (this wave's private d-slice) = 1KB.
#define GLD16(g, l) __builtin_amdgcn_global_load_lds( \
    (const __attribute__((address_space(1))) unsigned int*)(g), \
    (__attribute__((address_space(3))) unsigned int*)(l), 16, 0, 0)

// Counted vmcnt (T4): never drain to 0 in the main loop. "memory" clobber
// pins VMEM issue order so the counts below stay exact.
#define VM(n) asm volatile("s_waitcnt vmcnt(" #n ")" ::: "memory")
#define MEMFENCE asm volatile("" ::: "memory")

// ---------------------------------------------------------------------------
// Round 3: barrier-free per-wave pipeline. Round 2 proved the stall is the
// per-tile __syncthreads vmcnt(0) drain (VALUBusy pinned at 38% while HBM sits
// at 36% of achievable — SIMDs idle with zero runnable waves). Each wave now
// stages ONLY its own 32 d-columns (1 GLD16 = 8 rows x 32 cols), so no LDS
// crosses waves -> no barriers at all. Quad-buffered, 3 tiles in flight,
// counted s_waitcnt vmcnt(K):
//   windback steady:  K=2   (2 newer loads outstanding)
//   output  rel 0/1/2: K=2/10/18 (pipeline filling with stores entering count)
//   output  steady:   K=26  (2 loads + 3x8 stores newer than awaited load)
//   output  tail:     K=24
// vmcnt retires in issue order, so "counter <= K" <=> awaited load retired.
// Extra VMEM ops (param loads) issued after an awaited load only over-wait.
// ---------------------------------------------------------------------------
__global__ void __launch_bounds__(256, 8)
ema_fused(const float* __restrict__ x,
          const float* __restrict__ damp,
          const float* __restrict__ decay,
          const float* __restrict__ ema,
          const float* __restrict__ proj,
          const float* __restrict__ rw,
          float* __restrict__ out) {
    const int tid  = threadIdx.x;
    const int lane = tid & 63;
    const int wv   = tid >> 6;            // wave in block: 0..3
    const int h    = lane & 1;            // head half: 0 -> heads 0-7, 1 -> 8-15
    const int dl   = lane >> 1;           // 0..31: d within wave slice
    const int dloc = (wv << 5) + dl;      // 0..127: d within block
    const int d    = blockIdx.x * DBLK + dloc;
    const int c    = blockIdx.y;          // 0..NCHUNK-1
    const int b    = blockIdx.z;          // 0..7

    __shared__ float lds[4][NBUF][TL][32];   // per-wave private: 4 x 4KB = 16KB

    const float* dp = damp  + d * NH + h * 8;
    const float* dc = decay + d * NH + h * 8;
    const float* de = ema   + d * NH + h * 8;
    const float* pj = proj  + d * NH + h * 8;

    // ---- per-head state + projection weights (all before tile loads) ----
#define DECLQS(i) float q##i, s##i;
    REP8(DECLQS)
#define INITQS(i) { q##i = 1.0f - sigmoidf(dp[i]) * sigmoidf(dc[i]); s##i = 0.0f; }
    REP8(INITQS)
#define DECLP(i) float P##i;
    REP8(DECLP)
#define INITP(i) { float p_ = sigmoidf(dp[i]); P##i = p_ * de[i] * pj[i] * 0.25f; }
    REP8(INITP)
    // Even lane of each pair adds residual; odd contributes 0 so the xor-1
    // combine yields exactly y_conv + x*w.
    const float weff = (h == 0) ? rw[d] : 0.0f;

    const int wb = (c > 0) ? WB : 0;
    const int wt = wb / TL;               // 16 or 0 windback tiles

    // wave's x slice base (windback start), per-lane staging address:
    // lane l covers row (l>>3), float cols (l&7)*4 .. +3 of the 32-col slice
    const float* xw = x + (size_t)(c * COUT - wb) * BD + (size_t)b * D
                        + (size_t)blockIdx.x * DBLK + (wv << 5);
    const float* gsrc = xw + (size_t)(lane >> 3) * BD + ((lane & 7) << 2);

#define GLD(t) GLD16(gsrc + (size_t)(t) * (TL * BD), &lds[wv][(t) & 3][0][0])

    // ---- prologue: 3 tiles in flight ----
    GLD(0); GLD(1); GLD(2);
    MEMFENCE;

    // ---- windback: state update only, no stores ----
    if (c > 0) {
#pragma unroll 4
        for (int t = 0; t < WB / TL; ++t) {
            VM(2);
            GLD(t + 3);
            MEMFENCE;
            const float* bp = &lds[wv][t & 3][0][dl];
#pragma unroll
            for (int sl = 0; sl < TL; ++sl) { float xv = bp[sl * 32]; UPDALL }
        }
    }

    // ---- output phase: 16 tiles, update + project + residual + relu ----
    float* opb = out + (size_t)(c * COUT) * BD + (size_t)b * D + d;

#define OTILE(r, KWAIT, DOGLD) { \
        KWAIT; \
        if (DOGLD) GLD(wt + (r) + 3); \
        MEMFENCE; \
        const float* bp = &lds[wv][(r) & 3][0][dl]; \
        float* op = opb + (size_t)(r) * (TL * BD); \
        _Pragma("unroll") \
        for (int sl = 0; sl < TL; ++sl) { \
            float xv = bp[sl * 32]; \
            float y = xv * weff; \
            ACCALL \
            y += __shfl_xor(y, 1); \
            if (h == 0) \
                __builtin_nontemporal_store(fmaxf(y, 0.0f), op + (size_t)sl * BD); \
        } }

    OTILE(0,  VM(2),  1)
    OTILE(1,  VM(10), 1)
    OTILE(2,  VM(18), 1)
    OTILE(3,  VM(26), 1)
#pragma unroll 4
    for (int r = 4; r <= 11; ++r) { OTILE(r, VM(26), 1) }
    OTILE(12, VM(26), 1)
    OTILE(13, VM(26), 0)
    OTILE(14, VM(24), 0)
    OTILE(15, VM(24), 0)
}

// ---------------------------------------------------------------------------
extern "C" void kernel_launch(void* const* d_in, const int* in_sizes, int n_in,
                              void* d_out, int out_size, void* d_ws, size_t ws_size,
                              hipStream_t stream) {
    const float* x     = (const float*)d_in[0];
    const float* damp  = (const float*)d_in[1];
    const float* decay = (const float*)d_in[2];
    const float* ema   = (const float*)d_in[3];
    const float* proj  = (const float*)d_in[4];
    const float* rw    = (const float*)d_in[5];
    float* out = (float*)d_out;

    // 2048 blocks x 4 waves = 8192 waves; 8 blocks/CU (16KB LDS each)
    dim3 grid(D / DBLK, NCHUNK, B);
    ema_fused<<<grid, 256, 0, stream>>>(x, damp, decay, ema, proj, rw, out);
}

// Round 4
// 268.664 us; speedup vs baseline: 1.1438x; 1.1438x over previous
//
#include <hip/hip_runtime.h>
#include <math.h>

#define L 4096
#define B 8
#define D 1024
#define NH 16
#define COUT 256              // output chunk per block (was 128): windback
                              // amortization 1.5x instead of 2x
#define WB 128                // windback length (q^128 <= 2.4e-6 worst-case)
#define NCHUNK (L / COUT)     // 16
#define BD 8192               // B*D floats between consecutive l
#define DBLK 128              // d-values per block
#define TL 16                 // l-rows per LDS tile (8KB)
#define NBUF 4                // quad-buffered, 3 tiles in flight

#define REP8(F)  F(0) F(1) F(2) F(3) F(4) F(5) F(6) F(7)

__device__ __forceinline__ float sigmoidf(float v) {
    return 1.0f / (1.0f + __expf(-v));
}

// Per-head update/accumulate (8 heads per thread; lane pairs split 16 heads).
#define UPD(i) s##i = fmaf(q##i, s##i, xv);
#define UPDALL UPD(0) UPD(1) UPD(2) UPD(3) UPD(4) UPD(5) UPD(6) UPD(7)
#define ACC(i) s##i = fmaf(q##i, s##i, xv); y = fmaf(P##i, s##i, y);
#define ACCALL ACC(0) ACC(1) ACC(2) ACC(3) ACC(4) ACC(5) ACC(6) ACC(7)

// async global->LDS, 16B/lane, block-wide tile: wave wv stages rows
// 4wv..4wv+3 (2 instrs x 2 rows x 512B contiguous per row pair).
#define GLD16(g, l) __builtin_amdgcn_global_load_lds( \
    (const __attribute__((address_space(1))) unsigned int*)(g), \
    (__attribute__((address_space(3))) unsigned int*)(l), 16, 0, 0)

#define VM(n) asm volatile("s_waitcnt vmcnt(" #n ")" ::: "memory")
#define MEMFENCE asm volatile("" ::: "memory")

// ---------------------------------------------------------------------------
// Round 4: R2's block-wide staging + barriers (proven lowest-traffic: R3's
// de-synchronized waves cost +10% fetch, +21% write amplification) but with
// the two R2 stalls removed:
//  (1) __syncthreads' vmcnt(0) drain -> raw s_barrier + per-wave counted
//      vmcnt (T4): each wave waits only for ITS OWN staged rows (vmcnt(4):
//      tiles t+1,t+2 outstanding; t+3 issues after the barrier), the barrier
//      publishes them to the block. Loads for 3 future tiles stay in flight
//      across barriers; stores older than the awaited load are drained too
//      (safe over-wait; they retire during tile compute anyway).
//  (2) windback overhead 2.0x -> 1.5x via COUT=256: staged bytes 246->184MB,
//      FMA work -25%. Grid = 1024 blocks = exactly 4 blocks/CU (32KB LDS),
//      whole problem resident in one generation.
// Buffer-overwrite safety: GLD(t+3) -> buf (t-1)&3 is issued AFTER barrier t,
// which all waves reach only after finishing compute t-1 on that buffer.
// ---------------------------------------------------------------------------
__global__ void __launch_bounds__(256, 4)
ema_fused(const float* __restrict__ x,
          const float* __restrict__ damp,
          const float* __restrict__ decay,
          const float* __restrict__ ema,
          const float* __restrict__ proj,
          const float* __restrict__ rw,
          float* __restrict__ out) {
    const int tid  = threadIdx.x;
    const int lane = tid & 63;
    const int wv   = tid >> 6;            // wave in block: 0..3
    const int h    = lane & 1;            // head half: 0 -> heads 0-7, 1 -> 8-15
    const int dloc = (wv << 5) + (lane >> 1);   // 0..127: d within block
    const int d    = blockIdx.x * DBLK + dloc;
    const int c    = blockIdx.y;          // 0..NCHUNK-1
    const int b    = blockIdx.z;          // 0..7

    __shared__ float lds[NBUF][TL * DBLK];   // 4 x 8KB = 32KB

    const float* dp = damp  + d * NH + h * 8;
    const float* dc = decay + d * NH + h * 8;
    const float* de = ema   + d * NH + h * 8;
    const float* pj = proj  + d * NH + h * 8;

    // ---- per-head state + projection weights ----
#define DECLQS(i) float q##i, s##i;
    REP8(DECLQS)
#define INITQS(i) { q##i = 1.0f - sigmoidf(dp[i]) * sigmoidf(dc[i]); s##i = 0.0f; }
    REP8(INITQS)
#define DECLP(i) float P##i;
    REP8(DECLP)
#define INITP(i) { float p_ = sigmoidf(dp[i]); P##i = p_ * de[i] * pj[i] * 0.25f; }
    REP8(INITP)
    // Even lane of each pair adds residual; odd contributes 0 so the xor-1
    // combine yields exactly y_conv + x*w.
    const float weff = (h == 0) ? rw[d] : 0.0f;

    const int wb = (c > 0) ? WB : 0;
    const int wt = wb / TL;               // 8 or 0 windback tiles
    const int nt = wt + COUT / TL;        // 24 or 16 tiles total

    // block x base (windback start); per-lane staging src:
    // instr covers 2 rows x 128 floats: row = 4wv + (lane>>5), col = (lane&31)*4
    const float* xb = x + (size_t)(c * COUT - wb) * BD + (size_t)b * D
                        + (size_t)blockIdx.x * DBLK;
    const float* gsrc = xb + (size_t)((wv << 2) + (lane >> 5)) * BD
                           + ((lane & 31) << 2);

#define GLD(t) { \
        const float* g_ = gsrc + (size_t)(t) * (TL * BD); \
        float* l_ = &lds[(t) & 3][(wv << 2) * DBLK]; \
        GLD16(g_, l_); \
        GLD16(g_ + 2 * (size_t)BD, l_ + 2 * DBLK); }

    // ---- prologue: 3 tiles in flight ----
    GLD(0) GLD(1) GLD(2)
    MEMFENCE;

    float* opb = out + (size_t)(c * COUT) * BD + (size_t)b * D + d;

    for (int t = 0; t < nt; ++t) {
        // wait for OWN rows of tile t (loads for t+1,t+2 stay outstanding)
        if (t < nt - 2)       { VM(4); }
        else if (t == nt - 2) { VM(2); }
        else                  { VM(0); }
        __builtin_amdgcn_s_barrier();   // publish tile t; buf (t-1)&3 free
        MEMFENCE;
        if (t + 3 < nt) GLD(t + 3)
        MEMFENCE;

        const float* bp = &lds[t & 3][dloc];
        if (t < wt) {
            // ---- windback tile: state update only ----
#pragma unroll
            for (int sl = 0; sl < TL; ++sl) { float xv = bp[sl * DBLK]; UPDALL }
        } else {
            // ---- output tile: update + project + residual + relu ----
            float* op = opb + (size_t)(t - wt) * (TL * BD);
#pragma unroll
            for (int sl = 0; sl < TL; ++sl) {
                float xv = bp[sl * DBLK];
                float y = xv * weff;
                ACCALL
                y += __shfl_xor(y, 1);
                if (h == 0)
                    __builtin_nontemporal_store(fmaxf(y, 0.0f),
                                                op + (size_t)sl * BD);
            }
        }
    }
}

// ---------------------------------------------------------------------------
extern "C" void kernel_launch(void* const* d_in, const int* in_sizes, int n_in,
                              void* d_out, int out_size, void* d_ws, size_t ws_size,
                              hipStream_t stream) {
    const float* x     = (const float*)d_in[0];
    const float* damp  = (const float*)d_in[1];
    const float* decay = (const float*)d_in[2];
    const float* ema   = (const float*)d_in[3];
    const float* proj  = (const float*)d_in[4];
    const float* rw    = (const float*)d_in[5];
    float* out = (float*)d_out;

    // 1024 blocks x 4 waves; 4 blocks/CU (32KB LDS each) — one generation
    dim3 grid(D / DBLK, NCHUNK, B);
    ema_fused<<<grid, 256, 0, stream>>>(x, damp, decay, ema, proj, rw, out);
}

// Round 5
// 265.795 us; speedup vs baseline: 1.1561x; 1.0108x over previous
//
#include <hip/hip_runtime.h>
#include <math.h>

#define L 4096
#define B 8
#define D 1024
#define NH 16
#define COUT 256              // output chunk per block; windback amort 1.5x
#define WB 128                // windback length (q^128 <= 2.4e-6 worst-case)
#define NCHUNK (L / COUT)     // 16
#define BD 8192               // B*D floats between consecutive l
#define DBLK 128              // d-values per block
#define TL 16                 // l-rows per LDS tile (8KB)
#define NBUF 4                // quad-buffered, 3 tiles in flight

#define REP8(F)  F(0) F(1) F(2) F(3) F(4) F(5) F(6) F(7)

__device__ __forceinline__ float sigmoidf(float v) {
    return 1.0f / (1.0f + __expf(-v));
}

// Per-head update/accumulate (8 heads per thread; lane pairs split 16 heads).
#define UPD(i) s##i = fmaf(q##i, s##i, xv);
#define UPDALL UPD(0) UPD(1) UPD(2) UPD(3) UPD(4) UPD(5) UPD(6) UPD(7)
#define ACC(i) s##i = fmaf(q##i, s##i, xv); y = fmaf(P##i, s##i, y);
#define ACCALL ACC(0) ACC(1) ACC(2) ACC(3) ACC(4) ACC(5) ACC(6) ACC(7)

// async global->LDS, 16B/lane, block-wide tile: wave wv stages rows
// 4wv..4wv+3 (2 instrs x 2 rows x 512B contiguous per row pair).
#define GLD16(g, l) __builtin_amdgcn_global_load_lds( \
    (const __attribute__((address_space(1))) unsigned int*)(g), \
    (__attribute__((address_space(3))) unsigned int*)(l), 16, 0, 0)

#define VM(n) asm volatile("s_waitcnt vmcnt(" #n ")" ::: "memory")
#define MEMFENCE asm volatile("" ::: "memory")

// ---------------------------------------------------------------------------
// Round 5: R4 structure with CORRECT vmcnt accounting. R4's VM(4) in the
// output phase ignored that stores count in vmcnt: steady-state outstanding
// before the wait is 54 ops (2+16+2+16+2+16), so VM(4) drained the oldest 50
// — waiting for the load issued only ONE tile earlier plus 12 stores.
// Effective pipeline depth was ~1 tile. Exact counts (N = ops issued after
// the awaited tile-t loads):
//   windback:          VM(4)
//   output r=0/1/2:    VM(4)/VM(20)/VM(36)   (stores entering the queue)
//   output r=3..13:    VM(52)                (steady: 3 loads + 3x16 stores)
//   output r=14/15:    VM(50)/VM(48)         (no more GLD issued)
// One-time vmcnt(0) after parameter loads keeps the queue accounting exact
// (compiler would otherwise sink dp/dc/de/pj/rw loads into the GLD stream).
// Stores: after y += shfl_xor(y,1) both pair lanes hold the bitwise-identical
// value -> both store to the same address (no exec-mask churn).
// ---------------------------------------------------------------------------
__global__ void __launch_bounds__(256, 4)
ema_fused(const float* __restrict__ x,
          const float* __restrict__ damp,
          const float* __restrict__ decay,
          const float* __restrict__ ema,
          const float* __restrict__ proj,
          const float* __restrict__ rw,
          float* __restrict__ out) {
    const int tid  = threadIdx.x;
    const int lane = tid & 63;
    const int wv   = tid >> 6;            // wave in block: 0..3
    const int h    = lane & 1;            // head half: 0 -> heads 0-7, 1 -> 8-15
    const int dloc = (wv << 5) + (lane >> 1);   // 0..127: d within block
    const int d    = blockIdx.x * DBLK + dloc;
    const int c    = blockIdx.y;          // 0..NCHUNK-1
    const int b    = blockIdx.z;          // 0..7

    __shared__ float lds[NBUF][TL * DBLK];   // 4 x 8KB = 32KB

    const float* dp = damp  + d * NH + h * 8;
    const float* dc = decay + d * NH + h * 8;
    const float* de = ema   + d * NH + h * 8;
    const float* pj = proj  + d * NH + h * 8;

    // ---- per-head state + projection weights ----
#define DECLQS(i) float q##i, s##i;
    REP8(DECLQS)
#define INITQS(i) { q##i = 1.0f - sigmoidf(dp[i]) * sigmoidf(dc[i]); s##i = 0.0f; }
    REP8(INITQS)
#define DECLP(i) float P##i;
    REP8(DECLP)
#define INITP(i) { float p_ = sigmoidf(dp[i]); P##i = p_ * de[i] * pj[i] * 0.25f; }
    REP8(INITP)
    // Even lane of pair adds residual; odd contributes 0; xor-1 combine gives
    // both lanes the identical full result y_conv + x*w.
    const float weff = (h == 0) ? rw[d] : 0.0f;

    // drain parameter loads so the GLD queue accounting below is exact
    VM(0); MEMFENCE;

    const int wb = (c > 0) ? WB : 0;
    const int wt = wb / TL;               // 8 or 0 windback tiles
    const int nt = wt + COUT / TL;        // 24 or 16 tiles total

    // block x base (windback start); per-lane staging src:
    // instr covers 2 rows x 128 floats: row = 4wv + (lane>>5), col = (lane&31)*4
    const float* xb = x + (size_t)(c * COUT - wb) * BD + (size_t)b * D
                        + (size_t)blockIdx.x * DBLK;
    const float* gsrc = xb + (size_t)((wv << 2) + (lane >> 5)) * BD
                           + ((lane & 31) << 2);

#define GLD(t) { \
        const float* g_ = gsrc + (size_t)(t) * (TL * BD); \
        float* l_ = &lds[(t) & 3][(wv << 2) * DBLK]; \
        GLD16(g_, l_); \
        GLD16(g_ + 2 * (size_t)BD, l_ + 2 * DBLK); }

    // ---- prologue: 3 tiles in flight ----
    GLD(0) GLD(1) GLD(2)
    MEMFENCE;

    // ---- windback: state update only (no stores -> VM(4) exact) ----
    if (c > 0) {
        for (int t = 0; t < WB / TL; ++t) {
            VM(4);
            __builtin_amdgcn_s_barrier();
            MEMFENCE;
            GLD(t + 3)
            MEMFENCE;
            const float* bp = &lds[t & 3][dloc];
#pragma unroll
            for (int sl = 0; sl < TL; ++sl) { float xv = bp[sl * DBLK]; UPDALL }
        }
    }

    // ---- output phase: 16 tiles ----
    float* opb = out + (size_t)(c * COUT) * BD + (size_t)b * D + d;

#define OTILE(r, KWAIT, DOGLD) { \
        KWAIT; \
        __builtin_amdgcn_s_barrier(); \
        MEMFENCE; \
        if (DOGLD) GLD(wt + (r) + 3) \
        MEMFENCE; \
        const float* bp = &lds[(wt + (r)) & 3][dloc]; \
        float* op = opb + (size_t)(r) * (TL * BD); \
        _Pragma("unroll") \
        for (int sl = 0; sl < TL; ++sl) { \
            float xv = bp[sl * DBLK]; \
            float y = xv * weff; \
            ACCALL \
            y += __shfl_xor(y, 1); \
            __builtin_nontemporal_store(fmaxf(y, 0.0f), op + (size_t)sl * BD); \
        } }

    OTILE(0,  VM(4),  1)
    OTILE(1,  VM(20), 1)
    OTILE(2,  VM(36), 1)
#pragma unroll
    for (int r = 3; r <= 12; ++r) { OTILE(r, VM(52), 1) }
    OTILE(13, VM(52), 0)
    OTILE(14, VM(50), 0)
    OTILE(15, VM(48), 0)
}

// ---------------------------------------------------------------------------
extern "C" void kernel_launch(void* const* d_in, const int* in_sizes, int n_in,
                              void* d_out, int out_size, void* d_ws, size_t ws_size,
                              hipStream_t stream) {
    const float* x     = (const float*)d_in[0];
    const float* damp  = (const float*)d_in[1];
    const float* decay = (const float*)d_in[2];
    const float* ema   = (const float*)d_in[3];
    const float* proj  = (const float*)d_in[4];
    const float* rw    = (const float*)d_in[5];
    float* out = (float*)d_out;

    // 1024 blocks x 4 waves; 4 blocks/CU (32KB LDS each) — one generation
    dim3 grid(D / DBLK, NCHUNK, B);
    ema_fused<<<grid, 256, 0, stream>>>(x, damp, decay, ema, proj, rw, out);
}